// Round 1
// baseline (8913.234 us; speedup 1.0000x reference)
//
#include <hip/hip_runtime.h>
#include <math.h>

// Problem constants
#define S_LEN 2048
#define DMODEL 2048
#define NHEAD 16
#define KVHEAD 2
#define DHEAD 128
#define NLAYER 4
#define VOCAB 10000
#define INNER_DIM 8192
#define LN_EPS 1e-5f

typedef __attribute__((ext_vector_type(4))) float f32x4;
typedef __attribute__((ext_vector_type(2))) float f32x2;
typedef __attribute__((ext_vector_type(8))) short s16x8;
typedef __attribute__((ext_vector_type(4))) short s16x4;

__device__ __forceinline__ short f2bf(float f) {
  union { float f; unsigned u; } v; v.f = f;
  unsigned r = v.u + 0x7FFFu + ((v.u >> 16) & 1u);  // RNE
  return (short)(r >> 16);
}

__device__ __forceinline__ float gelu_tanh(float x) {
  float x3 = x * x * x;
  return 0.5f * x * (1.0f + tanhf(0.7978845608028654f * (x + 0.044715f * x3)));
}

// ---------------- LayerNorm over D=2048, one row per block ----------------
__global__ __launch_bounds__(256)
void ln2048(const float* __restrict__ in, const float* __restrict__ g,
            const float* __restrict__ b, float* __restrict__ out) {
  const int row = blockIdx.x;
  const int tid = threadIdx.x;
  const float* x = in + (size_t)row * DMODEL;
  float vals[8];
  float s = 0.f, s2 = 0.f;
#pragma unroll
  for (int i = 0; i < 8; ++i) {
    float t = x[tid + i * 256];
    vals[i] = t; s += t; s2 += t * t;
  }
#pragma unroll
  for (int off = 1; off < 64; off <<= 1) {
    s += __shfl_xor(s, off);
    s2 += __shfl_xor(s2, off);
  }
  __shared__ float rs[4], rs2[4];
  const int wave = tid >> 6;
  if ((tid & 63) == 0) { rs[wave] = s; rs2[wave] = s2; }
  __syncthreads();
  s = rs[0] + rs[1] + rs[2] + rs[3];
  s2 = rs2[0] + rs2[1] + rs2[2] + rs2[3];
  const float mean = s * (1.f / DMODEL);
  const float var = s2 * (1.f / DMODEL) - mean * mean;
  const float rstd = rsqrtf(var + LN_EPS);
  float* o = out + (size_t)row * DMODEL;
#pragma unroll
  for (int i = 0; i < 8; ++i) {
    int idx = tid + i * 256;
    o[idx] = (vals[i] - mean) * rstd * g[idx] + b[idx];
  }
}

// ---------------- Embedding gather + LayerNorm ----------------
__global__ __launch_bounds__(256)
void embed_ln(const int* __restrict__ text, const float* __restrict__ ew,
              const float* __restrict__ g, const float* __restrict__ b,
              float* __restrict__ out) {
  const int row = blockIdx.x;
  const int tid = threadIdx.x;
  const int tok = text[row];
  const float* x = ew + (size_t)tok * DMODEL;
  float vals[8];
  float s = 0.f, s2 = 0.f;
#pragma unroll
  for (int i = 0; i < 8; ++i) {
    float t = x[tid + i * 256];
    vals[i] = t; s += t; s2 += t * t;
  }
#pragma unroll
  for (int off = 1; off < 64; off <<= 1) {
    s += __shfl_xor(s, off);
    s2 += __shfl_xor(s2, off);
  }
  __shared__ float rs[4], rs2[4];
  const int wave = tid >> 6;
  if ((tid & 63) == 0) { rs[wave] = s; rs2[wave] = s2; }
  __syncthreads();
  s = rs[0] + rs[1] + rs[2] + rs[3];
  s2 = rs2[0] + rs2[1] + rs2[2] + rs2[3];
  const float mean = s * (1.f / DMODEL);
  const float var = s2 * (1.f / DMODEL) - mean * mean;
  const float rstd = rsqrtf(var + LN_EPS);
  float* o = out + (size_t)row * DMODEL;
#pragma unroll
  for (int i = 0; i < 8; ++i) {
    int idx = tid + i * 256;
    o[idx] = (vals[i] - mean) * rstd * g[idx] + b[idx];
  }
}

// ---------------- qk-norm: LayerNorm over DH=128, scale only, in place ----
__global__ __launch_bounds__(256)
void qknorm(float* __restrict__ x, const float* __restrict__ g, int nrows) {
  const int row = blockIdx.x * 4 + (threadIdx.x >> 6);
  const int lane = threadIdx.x & 63;
  if (row >= nrows) return;
  float* p = x + (size_t)row * DHEAD;
  f32x2 t = *(f32x2*)(p + lane * 2);
  float s = t[0] + t[1];
  float s2 = t[0] * t[0] + t[1] * t[1];
#pragma unroll
  for (int off = 1; off < 64; off <<= 1) {
    s += __shfl_xor(s, off);
    s2 += __shfl_xor(s2, off);
  }
  const float mean = s * (1.f / DHEAD);
  const float var = s2 * (1.f / DHEAD) - mean * mean;
  const float rstd = rsqrtf(var + LN_EPS);
  f32x2 o;
  o[0] = (t[0] - mean) * rstd * g[lane * 2];
  o[1] = (t[1] - mean) * rstd * g[lane * 2 + 1];
  *(f32x2*)(p + lane * 2) = o;
}

// ---------------- bf16 MFMA GEMM: C[M,N] = act(A[M,K] @ W[K,N] + bias) + res
// A, W are f32 in global; converted to bf16 during LDS staging.
// 128x128 tile, BK=32, 4 waves (2x2), 64x64 per wave, 16x16x32 MFMA.
template<int ACT, bool BIAS, bool RES>
__global__ __launch_bounds__(256)
void gemm_bf16(const float* __restrict__ A, const float* __restrict__ W,
               const float* __restrict__ bias, const float* __restrict__ res,
               float* __restrict__ C, int M, int N, int K) {
  __shared__ short As[128][40];  // [m][k], pad to 40 shorts (80B, 16B-aligned rows)
  __shared__ short Ws[128][40];  // [n][k] (transposed during staging)
  const int tid = threadIdx.x;
  const int bm = blockIdx.y * 128;
  const int bn = blockIdx.x * 128;
  const int wave = tid >> 6;
  const int lane = tid & 63;
  const int wr = (wave >> 1) * 64;
  const int wc = (wave & 1) * 64;
  const int g = lane >> 4;
  const int r = lane & 15;
  f32x4 acc[4][4];
#pragma unroll
  for (int m = 0; m < 4; ++m)
#pragma unroll
    for (int n = 0; n < 4; ++n) acc[m][n] = (f32x4){0.f, 0.f, 0.f, 0.f};

  for (int k0 = 0; k0 < K; k0 += 32) {
    __syncthreads();  // protect prior iteration's LDS reads
    // stage A tile 128x32 (f32 -> bf16), coalesced
#pragma unroll
    for (int i = 0; i < 4; ++i) {
      int idx = tid + i * 256;        // 1024 float4 slots
      int row = idx >> 3;             // 8 float4 per 32-wide row
      int c4 = (idx & 7) * 4;
      f32x4 v = *(const f32x4*)(A + (size_t)(bm + row) * K + k0 + c4);
      s16x4 bb;
      bb[0] = f2bf(v[0]); bb[1] = f2bf(v[1]); bb[2] = f2bf(v[2]); bb[3] = f2bf(v[3]);
      *(s16x4*)&As[row][c4] = bb;
    }
    // stage W tile 32x128 transposed into Ws[n][k]
#pragma unroll
    for (int i = 0; i < 4; ++i) {
      int idx = tid + i * 256;
      int kk = idx >> 5;              // 32 float4 per 128-wide row
      int n = (idx & 31) * 4;
      int gn = bn + n;
      const float* wp = W + (size_t)(k0 + kk) * N + gn;
      f32x4 v;
      if (gn + 3 < N) {
        v = *(const f32x4*)wp;
      } else {
        v[0] = (gn + 0 < N) ? wp[0] : 0.f;
        v[1] = (gn + 1 < N) ? wp[1] : 0.f;
        v[2] = (gn + 2 < N) ? wp[2] : 0.f;
        v[3] = (gn + 3 < N) ? wp[3] : 0.f;
      }
      Ws[n + 0][kk] = f2bf(v[0]);
      Ws[n + 1][kk] = f2bf(v[1]);
      Ws[n + 2][kk] = f2bf(v[2]);
      Ws[n + 3][kk] = f2bf(v[3]);
    }
    __syncthreads();
    s16x8 af[4], bf[4];
#pragma unroll
    for (int m = 0; m < 4; ++m) af[m] = *(const s16x8*)&As[wr + m * 16 + r][g * 8];
#pragma unroll
    for (int n = 0; n < 4; ++n) bf[n] = *(const s16x8*)&Ws[wc + n * 16 + r][g * 8];
#pragma unroll
    for (int m = 0; m < 4; ++m)
#pragma unroll
      for (int n = 0; n < 4; ++n)
        acc[m][n] = __builtin_amdgcn_mfma_f32_16x16x32_bf16(af[m], bf[n], acc[m][n], 0, 0, 0);
  }
  // epilogue: C layout col=lane&15, row=(lane>>4)*4+j
#pragma unroll
  for (int m = 0; m < 4; ++m) {
#pragma unroll
    for (int n = 0; n < 4; ++n) {
#pragma unroll
      for (int j = 0; j < 4; ++j) {
        int row = bm + wr + m * 16 + g * 4 + j;
        int col = bn + wc + n * 16 + r;
        if (col < N) {
          float v = acc[m][n][j];
          if (BIAS) v += bias[col];
          if (ACT == 1) v = gelu_tanh(v);
          if (RES) v += res[(size_t)row * N + col];
          C[(size_t)row * N + col] = v;
        }
      }
    }
  }
}

// ---------------- Flash attention (causal, GQA), online softmax ----------
// grid (S/64, H). Block = 4 waves; wave w owns q-rows [qbase+16w, +16).
__global__ __launch_bounds__(256)
void attn_fwd(const float* __restrict__ qbuf, const float* __restrict__ kbuf,
              const float* __restrict__ vbuf, float* __restrict__ obuf) {
  __shared__ short Qs[64][136];     // [qrow][d], pad rows to 272B
  __shared__ short Ks[32][136];     // [j][d]
  __shared__ short Vt[128][40];     // [d][j] (transposed)
  __shared__ short Ps[4][16][40];   // per-wave P tile [qrow16][j32]
  const int tid = threadIdx.x;
  const int qbase = blockIdx.x * 64;
  const int h = blockIdx.y;
  const int kh = h >> 3;            // H/KH = 8
  const int wave = tid >> 6;
  const int lane = tid & 63;
  const int g = lane >> 4;
  const int r = lane & 15;

  // stage Q (64 x 128)
#pragma unroll
  for (int i = 0; i < 8; ++i) {
    int idx = tid + i * 256;
    int row = idx >> 5;
    int c4 = (idx & 31) * 4;
    f32x4 v = *(const f32x4*)(qbuf + (size_t)(qbase + row) * DMODEL + h * DHEAD + c4);
    s16x4 bb;
    bb[0] = f2bf(v[0]); bb[1] = f2bf(v[1]); bb[2] = f2bf(v[2]); bb[3] = f2bf(v[3]);
    *(s16x4*)&Qs[row][c4] = bb;
  }

  f32x4 O[8];
#pragma unroll
  for (int d = 0; d < 8; ++d) O[d] = (f32x4){0.f, 0.f, 0.f, 0.f};
  float mst[4], lst[4];
#pragma unroll
  for (int j = 0; j < 4; ++j) { mst[j] = -1e30f; lst[j] = 0.f; }
  const int nt = (qbase + 64) >> 5;
  const int qrow0 = qbase + wave * 16;

  for (int jt = 0; jt < nt; ++jt) {
    const int jb = jt * 32;
    __syncthreads();  // prior reads of Ks/Vt done (also orders with Q staging)
    // stage K tile (32x128) and V transposed
#pragma unroll
    for (int i = 0; i < 4; ++i) {
      int idx = tid + i * 256;
      int row = idx >> 5;
      int c4 = (idx & 31) * 4;
      f32x4 v = *(const f32x4*)(kbuf + (size_t)(jb + row) * (KVHEAD * DHEAD) + kh * DHEAD + c4);
      s16x4 bb;
      bb[0] = f2bf(v[0]); bb[1] = f2bf(v[1]); bb[2] = f2bf(v[2]); bb[3] = f2bf(v[3]);
      *(s16x4*)&Ks[row][c4] = bb;
      f32x4 w = *(const f32x4*)(vbuf + (size_t)(jb + row) * (KVHEAD * DHEAD) + kh * DHEAD + c4);
      Vt[c4 + 0][row] = f2bf(w[0]);
      Vt[c4 + 1][row] = f2bf(w[1]);
      Vt[c4 + 2][row] = f2bf(w[2]);
      Vt[c4 + 3][row] = f2bf(w[3]);
    }
    __syncthreads();

    // QK^T: S-tile [16 qrows x 32 j] per wave
    f32x4 sc[2];
    sc[0] = (f32x4){0.f, 0.f, 0.f, 0.f};
    sc[1] = (f32x4){0.f, 0.f, 0.f, 0.f};
#pragma unroll
    for (int n = 0; n < 2; ++n)
#pragma unroll
      for (int kc = 0; kc < 4; ++kc) {
        s16x8 a = *(const s16x8*)&Qs[wave * 16 + r][kc * 32 + g * 8];
        s16x8 bb = *(const s16x8*)&Ks[n * 16 + r][kc * 32 + g * 8];
        sc[n] = __builtin_amdgcn_mfma_f32_16x16x32_bf16(a, bb, sc[n], 0, 0, 0);
      }
    const float scale = 0.08838834764831845f;  // 128^-0.5
    float pmax[4];
#pragma unroll
    for (int j = 0; j < 4; ++j) {
      int irow = qrow0 + g * 4 + j;
#pragma unroll
      for (int n = 0; n < 2; ++n) {
        int jcol = jb + n * 16 + r;
        sc[n][j] = (jcol <= irow) ? sc[n][j] * scale : -1e30f;
      }
      pmax[j] = fmaxf(sc[0][j], sc[1][j]);
    }
#pragma unroll
    for (int off = 1; off < 16; off <<= 1)
#pragma unroll
      for (int j = 0; j < 4; ++j) pmax[j] = fmaxf(pmax[j], __shfl_xor(pmax[j], off));

    float alpha[4], rsum[4];
#pragma unroll
    for (int j = 0; j < 4; ++j) {
      float mnew = fmaxf(mst[j], pmax[j]);
      alpha[j] = __expf(mst[j] - mnew);
      mst[j] = mnew;
      sc[0][j] = __expf(sc[0][j] - mnew);
      sc[1][j] = __expf(sc[1][j] - mnew);
      rsum[j] = sc[0][j] + sc[1][j];
    }
#pragma unroll
    for (int off = 1; off < 16; off <<= 1)
#pragma unroll
      for (int j = 0; j < 4; ++j) rsum[j] += __shfl_xor(rsum[j], off);
#pragma unroll
    for (int j = 0; j < 4; ++j) lst[j] = lst[j] * alpha[j] + rsum[j];
    // rescale O
#pragma unroll
    for (int d = 0; d < 8; ++d)
#pragma unroll
      for (int j = 0; j < 4; ++j) O[d][j] *= alpha[j];
    // write P (C-layout -> A-layout via LDS), wave-private region
#pragma unroll
    for (int j = 0; j < 4; ++j) {
      Ps[wave][g * 4 + j][r] = f2bf(sc[0][j]);
      Ps[wave][g * 4 + j][16 + r] = f2bf(sc[1][j]);
    }
    // PV: O[16 x 128] += P[16 x 32] @ V[32 x 128]
    s16x8 a = *(const s16x8*)&Ps[wave][r][g * 8];
#pragma unroll
    for (int d = 0; d < 8; ++d) {
      s16x8 bb = *(const s16x8*)&Vt[d * 16 + r][g * 8];
      O[d] = __builtin_amdgcn_mfma_f32_16x16x32_bf16(a, bb, O[d], 0, 0, 0);
    }
  }
  // epilogue: O / l
  float linv[4];
#pragma unroll
  for (int j = 0; j < 4; ++j) linv[j] = 1.f / lst[j];
#pragma unroll
  for (int d = 0; d < 8; ++d)
#pragma unroll
    for (int j = 0; j < 4; ++j)
      obuf[(size_t)(qrow0 + g * 4 + j) * DMODEL + h * DHEAD + d * 16 + r] = O[d][j] * linv[j];
}

// ---------------- host side ----------------
extern "C" void kernel_launch(void* const* d_in, const int* in_sizes, int n_in,
                              void* d_out, int out_size, void* d_ws, size_t ws_size,
                              hipStream_t stream) {
  const int* text = (const int*)d_in[0];
  const float* embed_w = (const float*)d_in[1];
  const float* model_g = (const float*)d_in[2];
  const float* model_b = (const float*)d_in[3];
  const float* blk_g = (const float*)d_in[4];
  const float* blk_b = (const float*)d_in[5];
  const float* attn_g = (const float*)d_in[6];
  const float* attn_b = (const float*)d_in[7];
  const float* wq = (const float*)d_in[8];
  const float* wk = (const float*)d_in[9];
  const float* wv = (const float*)d_in[10];
  const float* wo = (const float*)d_in[11];
  const float* qn_g = (const float*)d_in[12];
  const float* kn_g = (const float*)d_in[13];
  const float* w1 = (const float*)d_in[14];
  const float* b1 = (const float*)d_in[15];
  const float* w2 = (const float*)d_in[16];
  const float* b2 = (const float*)d_in[17];
  const float* head_g = (const float*)d_in[18];
  const float* head_b = (const float*)d_in[19];
  const float* head_w = (const float*)d_in[20];
  const float* head_bias = (const float*)d_in[21];
  float* out = (float*)d_out;

  const size_t SD = (size_t)S_LEN * DMODEL;           // 4.19M
  const size_t SKV = (size_t)S_LEN * KVHEAD * DHEAD;  // 0.52M
  float* ws = (float*)d_ws;
  float* x = ws;             // [S,D]
  float* hb = x + SD;        // [S,D]  block-normed h
  float* hn = hb + SD;       // [S,D]  attn prenorm / h2 after wo
  float* q = hn + SD;        // [S,D]  also reused as `pre` after FFN
  float* ao = q + SD;        // [S,D]  attention output (pre-wo)
  float* kb = ao + SD;       // [S,256]
  float* vb = kb + SKV;      // [S,256]
  float* ffi = vb + SKV;     // [S,INNER]
  // total ~148 MB of d_ws

  dim3 blk(256);
  embed_ln<<<S_LEN, blk, 0, stream>>>(text, embed_w, model_g, model_b, x);

  for (int i = 0; i < NLAYER; ++i) {
    const float* wq_i = wq + (size_t)i * DMODEL * (NHEAD * DHEAD);
    const float* wk_i = wk + (size_t)i * DMODEL * (KVHEAD * DHEAD);
    const float* wv_i = wv + (size_t)i * DMODEL * (KVHEAD * DHEAD);
    const float* wo_i = wo + (size_t)i * (NHEAD * DHEAD) * DMODEL;
    const float* w1_i = w1 + (size_t)i * DMODEL * INNER_DIM;
    const float* b1_i = b1 + (size_t)i * INNER_DIM;
    const float* w2_i = w2 + (size_t)i * INNER_DIM * DMODEL;
    const float* b2_i = b2 + (size_t)i * DMODEL;

    ln2048<<<S_LEN, blk, 0, stream>>>(x, blk_g + i * DMODEL, blk_b + i * DMODEL, hb);
    ln2048<<<S_LEN, blk, 0, stream>>>(hb, attn_g + i * DMODEL, attn_b + i * DMODEL, hn);
    gemm_bf16<0, false, false><<<dim3(16, 16), blk, 0, stream>>>(hn, wq_i, nullptr, nullptr, q, S_LEN, DMODEL, DMODEL);
    gemm_bf16<0, false, false><<<dim3(2, 16), blk, 0, stream>>>(hn, wk_i, nullptr, nullptr, kb, S_LEN, KVHEAD * DHEAD, DMODEL);
    gemm_bf16<0, false, false><<<dim3(2, 16), blk, 0, stream>>>(hn, wv_i, nullptr, nullptr, vb, S_LEN, KVHEAD * DHEAD, DMODEL);
    qknorm<<<(S_LEN * NHEAD) / 4, blk, 0, stream>>>(q, qn_g + i * DHEAD, S_LEN * NHEAD);
    qknorm<<<(S_LEN * KVHEAD) / 4, blk, 0, stream>>>(kb, kn_g + i * DHEAD, S_LEN * KVHEAD);
    attn_fwd<<<dim3(S_LEN / 64, NHEAD), blk, 0, stream>>>(q, kb, vb, ao);
    // h2 = ao @ wo + hb  -> hn
    gemm_bf16<0, false, true><<<dim3(16, 16), blk, 0, stream>>>(ao, wo_i, nullptr, hb, hn, S_LEN, DMODEL, DMODEL);
    // ffi = gelu(hn @ w1 + b1)
    gemm_bf16<1, true, false><<<dim3(64, 16), blk, 0, stream>>>(hn, w1_i, b1_i, nullptr, ffi, S_LEN, INNER_DIM, DMODEL);
    // pre = ffi @ w2 + b2 + hn  -> q (reuse)
    gemm_bf16<0, true, true><<<dim3(16, 16), blk, 0, stream>>>(ffi, w2_i, b2_i, hn, q, S_LEN, DMODEL, INNER_DIM);
    ln2048<<<S_LEN, blk, 0, stream>>>(q, model_g, model_b, x);
  }

  ln2048<<<S_LEN, blk, 0, stream>>>(x, head_g, head_b, hn);
  gemm_bf16<0, true, false><<<dim3((VOCAB + 127) / 128, 16), blk, 0, stream>>>(
      hn, head_w, head_bias, nullptr, out, S_LEN, VOCAB, DMODEL);
}

// Round 2
// 2981.356 us; speedup vs baseline: 2.9897x; 2.9897x over previous
//
#include <hip/hip_runtime.h>
#include <math.h>

#define S_LEN 2048
#define DMODEL 2048
#define NHEAD 16
#define KVHEAD 2
#define DHEAD 128
#define NLAYER 4
#define VOCAB 10000
#define INNER_DIM 8192
#define LN_EPS 1e-5f
#define VOCAB_PAD 10112  // 79*128

typedef __attribute__((ext_vector_type(4))) float f32x4;
typedef __attribute__((ext_vector_type(2))) float f32x2;
typedef __attribute__((ext_vector_type(8))) short s16x8;
typedef __attribute__((ext_vector_type(4))) short s16x4;

__device__ __forceinline__ short f2bf(float f) {
  union { float f; unsigned u; } v; v.f = f;
  unsigned r = v.u + 0x7FFFu + ((v.u >> 16) & 1u);  // RNE
  return (short)(r >> 16);
}

__device__ __forceinline__ float gelu_tanh(float x) {
  float x3 = x * x * x;
  return 0.5f * x * (1.0f + tanhf(0.7978845608028654f * (x + 0.044715f * x3)));
}

// async global->LDS, 16B per lane; LDS dest = wave-uniform base + lane*16
__device__ __forceinline__ void glds16(const void* g, void* l) {
  __builtin_amdgcn_global_load_lds(
      (const __attribute__((address_space(1))) unsigned int*)g,
      (__attribute__((address_space(3))) unsigned int*)l, 16, 0, 0);
}

// ---------------- weight transpose + f32->bf16: W[K][N] -> WT[NP][K] ------
__global__ __launch_bounds__(256)
void wtrans(const float* __restrict__ W, short* __restrict__ WT,
            int K, int N, int NP) {
  __shared__ float ld[32][33];
  const int n0 = blockIdx.x * 32, k0 = blockIdx.y * 32;
  const int tx = threadIdx.x & 31, ty = threadIdx.x >> 5;  // 32 x 8
#pragma unroll
  for (int p = 0; p < 4; ++p) {
    int kk = ty + p * 8;
    ld[kk][tx] = (n0 + tx < N) ? W[(size_t)(k0 + kk) * N + n0 + tx] : 0.f;
  }
  __syncthreads();
#pragma unroll
  for (int p = 0; p < 4; ++p) {
    int nn = ty + p * 8;
    int n = n0 + nn;
    if (n < NP) {
      short v = (n < N) ? f2bf(ld[tx][nn]) : (short)0;
      WT[(size_t)n * K + k0 + tx] = v;
    }
  }
}

// ---------------- LayerNorm D=2048, f32 out ----------------
__global__ __launch_bounds__(256)
void ln2048(const float* __restrict__ in, const float* __restrict__ g,
            const float* __restrict__ b, float* __restrict__ out) {
  const int row = blockIdx.x;
  const int tid = threadIdx.x;
  const float* x = in + (size_t)row * DMODEL;
  float vals[8];
  float s = 0.f, s2 = 0.f;
#pragma unroll
  for (int i = 0; i < 8; ++i) {
    float t = x[tid + i * 256];
    vals[i] = t; s += t; s2 += t * t;
  }
#pragma unroll
  for (int off = 1; off < 64; off <<= 1) {
    s += __shfl_xor(s, off); s2 += __shfl_xor(s2, off);
  }
  __shared__ float rs[4], rs2[4];
  const int wave = tid >> 6;
  if ((tid & 63) == 0) { rs[wave] = s; rs2[wave] = s2; }
  __syncthreads();
  s = rs[0] + rs[1] + rs[2] + rs[3];
  s2 = rs2[0] + rs2[1] + rs2[2] + rs2[3];
  const float mean = s * (1.f / DMODEL);
  const float var = s2 * (1.f / DMODEL) - mean * mean;
  const float rstd = rsqrtf(var + LN_EPS);
  float* o = out + (size_t)row * DMODEL;
#pragma unroll
  for (int i = 0; i < 8; ++i) {
    int idx = tid + i * 256;
    o[idx] = (vals[i] - mean) * rstd * g[idx] + b[idx];
  }
}

// ---------------- LayerNorm D=2048, bf16 out ----------------
__global__ __launch_bounds__(256)
void ln2048b(const float* __restrict__ in, const float* __restrict__ g,
             const float* __restrict__ b, short* __restrict__ out) {
  const int row = blockIdx.x;
  const int tid = threadIdx.x;
  const float* x = in + (size_t)row * DMODEL;
  float vals[8];
  float s = 0.f, s2 = 0.f;
#pragma unroll
  for (int i = 0; i < 8; ++i) {
    float t = x[tid + i * 256];
    vals[i] = t; s += t; s2 += t * t;
  }
#pragma unroll
  for (int off = 1; off < 64; off <<= 1) {
    s += __shfl_xor(s, off); s2 += __shfl_xor(s2, off);
  }
  __shared__ float rs[4], rs2[4];
  const int wave = tid >> 6;
  if ((tid & 63) == 0) { rs[wave] = s; rs2[wave] = s2; }
  __syncthreads();
  s = rs[0] + rs[1] + rs[2] + rs[3];
  s2 = rs2[0] + rs2[1] + rs2[2] + rs2[3];
  const float mean = s * (1.f / DMODEL);
  const float var = s2 * (1.f / DMODEL) - mean * mean;
  const float rstd = rsqrtf(var + LN_EPS);
  short* o = out + (size_t)row * DMODEL;
#pragma unroll
  for (int i = 0; i < 8; ++i) {
    int idx = tid + i * 256;
    o[idx] = f2bf((vals[i] - mean) * rstd * g[idx] + b[idx]);
  }
}

// ---------------- Embedding gather + LayerNorm ----------------
__global__ __launch_bounds__(256)
void embed_ln(const int* __restrict__ text, const float* __restrict__ ew,
              const float* __restrict__ g, const float* __restrict__ b,
              float* __restrict__ out) {
  const int row = blockIdx.x;
  const int tid = threadIdx.x;
  const int tok = text[row];
  const float* x = ew + (size_t)tok * DMODEL;
  float vals[8];
  float s = 0.f, s2 = 0.f;
#pragma unroll
  for (int i = 0; i < 8; ++i) {
    float t = x[tid + i * 256];
    vals[i] = t; s += t; s2 += t * t;
  }
#pragma unroll
  for (int off = 1; off < 64; off <<= 1) {
    s += __shfl_xor(s, off); s2 += __shfl_xor(s2, off);
  }
  __shared__ float rs[4], rs2[4];
  const int wave = tid >> 6;
  if ((tid & 63) == 0) { rs[wave] = s; rs2[wave] = s2; }
  __syncthreads();
  s = rs[0] + rs[1] + rs[2] + rs[3];
  s2 = rs2[0] + rs2[1] + rs2[2] + rs2[3];
  const float mean = s * (1.f / DMODEL);
  const float var = s2 * (1.f / DMODEL) - mean * mean;
  const float rstd = rsqrtf(var + LN_EPS);
  float* o = out + (size_t)row * DMODEL;
#pragma unroll
  for (int i = 0; i < 8; ++i) {
    int idx = tid + i * 256;
    o[idx] = (vals[i] - mean) * rstd * g[idx] + b[idx];
  }
}

// ---------------- qk-norm over DH=128, f32 in -> bf16 out ----------------
__global__ __launch_bounds__(256)
void qknorm_b16(const float* __restrict__ in, const float* __restrict__ g,
                short* __restrict__ out, int nrows) {
  const int row = blockIdx.x * 4 + (threadIdx.x >> 6);
  const int lane = threadIdx.x & 63;
  if (row >= nrows) return;
  const float* p = in + (size_t)row * DHEAD;
  f32x2 t = *(const f32x2*)(p + lane * 2);
  float s = t[0] + t[1];
  float s2 = t[0] * t[0] + t[1] * t[1];
#pragma unroll
  for (int off = 1; off < 64; off <<= 1) {
    s += __shfl_xor(s, off); s2 += __shfl_xor(s2, off);
  }
  const float mean = s * (1.f / DHEAD);
  const float var = s2 * (1.f / DHEAD) - mean * mean;
  const float rstd = rsqrtf(var + LN_EPS);
  short* o = out + (size_t)row * DHEAD;
  o[lane * 2] = f2bf((t[0] - mean) * rstd * g[lane * 2]);
  o[lane * 2 + 1] = f2bf((t[1] - mean) * rstd * g[lane * 2 + 1]);
}

// ---------------- bf16 MFMA GEMM (m97 structure) -------------------------
// C[M,N] = act(A[M,K] @ BT[N,K]^T + bias) (+ res); A,BT bf16 row-major.
// 128x128 tile, BK=64, 4 waves 2x2, global_load_lds + XOR-swizzle (rule #21).
template<int ACT, bool BIAS, bool RES, bool WF, bool WB>
__global__ __launch_bounds__(256)
void gemm_bt(const short* __restrict__ A, const short* __restrict__ BT,
             const float* __restrict__ bias, const float* __restrict__ res,
             float* __restrict__ Cf, short* __restrict__ Cb,
             int M, int N, int K) {
  __shared__ short As[128 * 64];
  __shared__ short Bs[128 * 64];
  const int tid = threadIdx.x;
  const int bm = blockIdx.y * 128, bn = blockIdx.x * 128;
  const int wave = tid >> 6, lane = tid & 63;
  const int g = lane >> 4, r = lane & 15;
  const int wr = (wave >> 1) * 64, wc = (wave & 1) * 64;

  const short* pa[4]; const short* pb[4]; short* da[4]; short* db[4];
#pragma unroll
  for (int i = 0; i < 4; ++i) {
    int c = i * 256 + tid;
    int row = c >> 3, s = c & 7;
    int col = ((s ^ (row & 7)) << 3);  // pre-swizzled global column
    pa[i] = A + (size_t)(bm + row) * K + col;
    pb[i] = BT + (size_t)(bn + row) * K + col;
    int base = (i * 256 + (wave << 6)) << 3;  // shorts; HW adds lane*16B
    da[i] = As + base;
    db[i] = Bs + base;
  }

  f32x4 acc[4][4] = {};
  for (int k0 = 0; k0 < K; k0 += 64) {
    __syncthreads();
#pragma unroll
    for (int i = 0; i < 4; ++i) glds16(pa[i] + k0, da[i]);
#pragma unroll
    for (int i = 0; i < 4; ++i) glds16(pb[i] + k0, db[i]);
    __syncthreads();
#pragma unroll
    for (int kk = 0; kk < 2; ++kk) {
      s16x8 af[4], bf[4];
#pragma unroll
      for (int m = 0; m < 4; ++m) {
        int rr = wr + m * 16 + r;
        af[m] = *(const s16x8*)&As[rr * 64 + ((((kk << 2) | g) ^ (rr & 7)) << 3)];
      }
#pragma unroll
      for (int n = 0; n < 4; ++n) {
        int rr = wc + n * 16 + r;
        bf[n] = *(const s16x8*)&Bs[rr * 64 + ((((kk << 2) | g) ^ (rr & 7)) << 3)];
      }
#pragma unroll
      for (int m = 0; m < 4; ++m)
#pragma unroll
        for (int n = 0; n < 4; ++n)
          acc[m][n] = __builtin_amdgcn_mfma_f32_16x16x32_bf16(af[m], bf[n], acc[m][n], 0, 0, 0);
    }
  }
#pragma unroll
  for (int m = 0; m < 4; ++m) {
    int row = bm + wr + m * 16 + g * 4;
#pragma unroll
    for (int n = 0; n < 4; ++n) {
      int col = bn + wc + n * 16 + r;
      if (col < N) {
#pragma unroll
        for (int j = 0; j < 4; ++j) {
          float v = acc[m][n][j];
          if (BIAS) v += bias[col];
          if (ACT) v = gelu_tanh(v);
          if (RES) v += res[(size_t)(row + j) * N + col];
          if (WF) Cf[(size_t)(row + j) * N + col] = v;
          if (WB) Cb[(size_t)(row + j) * N + col] = f2bf(v);
        }
      }
    }
  }
}

// ---------------- Flash attention (causal, GQA), bf16 in/out -------------
__global__ __launch_bounds__(256)
void attn_fwd(const short* __restrict__ qbuf, const short* __restrict__ kbuf,
              const short* __restrict__ vbuf, short* __restrict__ obuf) {
  __shared__ short Qs[64][136];
  __shared__ short Ks[32][136];
  __shared__ short Vt[128][40];   // [d][j ^ f(d)], f(d)=((d>>3)&3)<<3
  __shared__ short Ps[4][16][40];
  const int tid = threadIdx.x;
  const int qbase = blockIdx.x * 64;
  const int h = blockIdx.y;
  const int kh = h >> 3;
  const int wave = tid >> 6;
  const int lane = tid & 63;
  const int g = lane >> 4;
  const int r = lane & 15;

#pragma unroll
  for (int i = 0; i < 4; ++i) {
    int idx = tid + i * 256;
    int row = idx >> 4;
    int c8 = (idx & 15) << 3;
    s16x8 v = *(const s16x8*)(qbuf + (size_t)(qbase + row) * DMODEL + h * DHEAD + c8);
    *(s16x8*)&Qs[row][c8] = v;
  }

  f32x4 O[8];
#pragma unroll
  for (int d = 0; d < 8; ++d) O[d] = (f32x4){0.f, 0.f, 0.f, 0.f};
  float mst[4], lst[4];
#pragma unroll
  for (int j = 0; j < 4; ++j) { mst[j] = -1e30f; lst[j] = 0.f; }
  const int nt = (qbase + 64) >> 5;
  const int qrow0 = qbase + wave * 16;

  for (int jt = 0; jt < nt; ++jt) {
    const int jb = jt * 32;
    __syncthreads();
#pragma unroll
    for (int i = 0; i < 2; ++i) {
      int idx = tid + i * 256;
      int row = idx >> 4;
      int c8 = (idx & 15) << 3;
      s16x8 kv = *(const s16x8*)(kbuf + (size_t)(jb + row) * (KVHEAD * DHEAD) + kh * DHEAD + c8);
      *(s16x8*)&Ks[row][c8] = kv;
      s16x8 vv = *(const s16x8*)(vbuf + (size_t)(jb + row) * (KVHEAD * DHEAD) + kh * DHEAD + c8);
#pragma unroll
      for (int u = 0; u < 8; ++u) {
        int d = c8 + u;
        Vt[d][row ^ (((d >> 3) & 3) << 3)] = vv[u];
      }
    }
    __syncthreads();

    f32x4 sc[2];
    sc[0] = (f32x4){0.f, 0.f, 0.f, 0.f};
    sc[1] = (f32x4){0.f, 0.f, 0.f, 0.f};
#pragma unroll
    for (int n = 0; n < 2; ++n)
#pragma unroll
      for (int kc = 0; kc < 4; ++kc) {
        s16x8 a = *(const s16x8*)&Qs[wave * 16 + r][kc * 32 + g * 8];
        s16x8 bb = *(const s16x8*)&Ks[n * 16 + r][kc * 32 + g * 8];
        sc[n] = __builtin_amdgcn_mfma_f32_16x16x32_bf16(a, bb, sc[n], 0, 0, 0);
      }
    const float scale = 0.08838834764831845f;
    float pmax[4];
#pragma unroll
    for (int j = 0; j < 4; ++j) {
      int irow = qrow0 + g * 4 + j;
#pragma unroll
      for (int n = 0; n < 2; ++n) {
        int jcol = jb + n * 16 + r;
        sc[n][j] = (jcol <= irow) ? sc[n][j] * scale : -1e30f;
      }
      pmax[j] = fmaxf(sc[0][j], sc[1][j]);
    }
#pragma unroll
    for (int off = 1; off < 16; off <<= 1)
#pragma unroll
      for (int j = 0; j < 4; ++j) pmax[j] = fmaxf(pmax[j], __shfl_xor(pmax[j], off));

    float alpha[4], rsum[4];
#pragma unroll
    for (int j = 0; j < 4; ++j) {
      float mnew = fmaxf(mst[j], pmax[j]);
      alpha[j] = __expf(mst[j] - mnew);
      mst[j] = mnew;
      sc[0][j] = __expf(sc[0][j] - mnew);
      sc[1][j] = __expf(sc[1][j] - mnew);
      rsum[j] = sc[0][j] + sc[1][j];
    }
#pragma unroll
    for (int off = 1; off < 16; off <<= 1)
#pragma unroll
      for (int j = 0; j < 4; ++j) rsum[j] += __shfl_xor(rsum[j], off);
#pragma unroll
    for (int j = 0; j < 4; ++j) lst[j] = lst[j] * alpha[j] + rsum[j];
#pragma unroll
    for (int d = 0; d < 8; ++d)
#pragma unroll
      for (int j = 0; j < 4; ++j) O[d][j] *= alpha[j];
#pragma unroll
    for (int j = 0; j < 4; ++j) {
      Ps[wave][g * 4 + j][r] = f2bf(sc[0][j]);
      Ps[wave][g * 4 + j][16 + r] = f2bf(sc[1][j]);
    }
    s16x8 a = *(const s16x8*)&Ps[wave][r][g * 8];
#pragma unroll
    for (int d = 0; d < 8; ++d) {
      int dd = d * 16 + r;
      s16x8 bb = *(const s16x8*)&Vt[dd][(g << 3) ^ (((dd >> 3) & 3) << 3)];
      O[d] = __builtin_amdgcn_mfma_f32_16x16x32_bf16(a, bb, O[d], 0, 0, 0);
    }
  }
  float linv[4];
#pragma unroll
  for (int j = 0; j < 4; ++j) linv[j] = 1.f / lst[j];
#pragma unroll
  for (int d = 0; d < 8; ++d)
#pragma unroll
    for (int j = 0; j < 4; ++j)
      obuf[(size_t)(qrow0 + g * 4 + j) * DMODEL + h * DHEAD + d * 16 + r] =
          f2bf(O[d][j] * linv[j]);
}

// ---------------- host side ----------------
extern "C" void kernel_launch(void* const* d_in, const int* in_sizes, int n_in,
                              void* d_out, int out_size, void* d_ws, size_t ws_size,
                              hipStream_t stream) {
  const int* text = (const int*)d_in[0];
  const float* embed_w = (const float*)d_in[1];
  const float* model_g = (const float*)d_in[2];
  const float* model_b = (const float*)d_in[3];
  const float* blk_g = (const float*)d_in[4];
  const float* blk_b = (const float*)d_in[5];
  const float* attn_g = (const float*)d_in[6];
  const float* attn_b = (const float*)d_in[7];
  const float* wq = (const float*)d_in[8];
  const float* wk = (const float*)d_in[9];
  const float* wv = (const float*)d_in[10];
  const float* wo = (const float*)d_in[11];
  const float* qn_g = (const float*)d_in[12];
  const float* kn_g = (const float*)d_in[13];
  const float* w1 = (const float*)d_in[14];
  const float* b1 = (const float*)d_in[15];
  const float* w2 = (const float*)d_in[16];
  const float* b2 = (const float*)d_in[17];
  const float* head_g = (const float*)d_in[18];
  const float* head_b = (const float*)d_in[19];
  const float* head_w = (const float*)d_in[20];
  const float* head_bias = (const float*)d_in[21];
  float* out = (float*)d_out;

  const size_t SD = (size_t)S_LEN * DMODEL;
  const size_t SKV = (size_t)S_LEN * KVHEAD * DHEAD;
  const size_t SI = (size_t)S_LEN * INNER_DIM;
  const size_t WD = (size_t)DMODEL * DMODEL;          // 2048x2048
  const size_t WKV = (size_t)DMODEL * KVHEAD * DHEAD; // 2048x256
  const size_t WI = (size_t)DMODEL * INNER_DIM;       // 2048x8192

  char* p = (char*)d_ws;
  float* x    = (float*)p; p += SD * 4;
  float* hb   = (float*)p; p += SD * 4;
  float* h2   = (float*)p; p += SD * 4;
  float* pre  = (float*)p; p += SD * 4;
  float* qf   = (float*)p; p += SD * 4;
  float* kf   = (float*)p; p += SKV * 4;
  short* hn16 = (short*)p; p += SD * 2;
  short* ao16 = (short*)p; p += SD * 2;
  short* h216 = (short*)p; p += SD * 2;
  short* ffi16= (short*)p; p += SI * 2;
  short* qb16 = (short*)p; p += SD * 2;
  short* kb16 = (short*)p; p += SKV * 2;
  short* vb16 = (short*)p; p += SKV * 2;
  short* wqT  = (short*)p; p += WD * 2;
  short* wkT  = (short*)p; p += WKV * 2;
  short* wvT  = (short*)p; p += WKV * 2;
  short* woT  = (short*)p; p += WD * 2;
  short* w1T  = (short*)p; p += WI * 2;   // also reused as headT after layers
  short* w2T  = (short*)p; p += WI * 2;
  short* headT = w1T;  // 10112*2048 bf16 = 41.4MB fits in w1T+w2T region (134MB)

  dim3 blk(256);
  embed_ln<<<S_LEN, blk, 0, stream>>>(text, embed_w, model_g, model_b, x);

  const int NQ = NHEAD * DHEAD;    // 2048
  const int NKV = KVHEAD * DHEAD;  // 256

  for (int i = 0; i < NLAYER; ++i) {
    const float* wq_i = wq + (size_t)i * WD;
    const float* wk_i = wk + (size_t)i * WKV;
    const float* wv_i = wv + (size_t)i * WKV;
    const float* wo_i = wo + (size_t)i * WD;
    const float* w1_i = w1 + (size_t)i * WI;
    const float* b1_i = b1 + (size_t)i * INNER_DIM;
    const float* w2_i = w2 + (size_t)i * WI;
    const float* b2_i = b2 + (size_t)i * DMODEL;

    // weight prep (per layer, reusing slots)
    wtrans<<<dim3(NQ / 32, DMODEL / 32), blk, 0, stream>>>(wq_i, wqT, DMODEL, NQ, NQ);
    wtrans<<<dim3(NKV / 32, DMODEL / 32), blk, 0, stream>>>(wk_i, wkT, DMODEL, NKV, NKV);
    wtrans<<<dim3(NKV / 32, DMODEL / 32), blk, 0, stream>>>(wv_i, wvT, DMODEL, NKV, NKV);
    wtrans<<<dim3(DMODEL / 32, NQ / 32), blk, 0, stream>>>(wo_i, woT, NQ, DMODEL, DMODEL);
    wtrans<<<dim3(INNER_DIM / 32, DMODEL / 32), blk, 0, stream>>>(w1_i, w1T, DMODEL, INNER_DIM, INNER_DIM);
    wtrans<<<dim3(DMODEL / 32, INNER_DIM / 32), blk, 0, stream>>>(w2_i, w2T, INNER_DIM, DMODEL, DMODEL);

    ln2048<<<S_LEN, blk, 0, stream>>>(x, blk_g + i * DMODEL, blk_b + i * DMODEL, hb);
    ln2048b<<<S_LEN, blk, 0, stream>>>(hb, attn_g + i * DMODEL, attn_b + i * DMODEL, hn16);

    gemm_bt<0, false, false, true, false><<<dim3(NQ / 128, S_LEN / 128), blk, 0, stream>>>(
        hn16, wqT, nullptr, nullptr, qf, nullptr, S_LEN, NQ, DMODEL);
    gemm_bt<0, false, false, true, false><<<dim3(NKV / 128, S_LEN / 128), blk, 0, stream>>>(
        hn16, wkT, nullptr, nullptr, kf, nullptr, S_LEN, NKV, DMODEL);
    gemm_bt<0, false, false, false, true><<<dim3(NKV / 128, S_LEN / 128), blk, 0, stream>>>(
        hn16, wvT, nullptr, nullptr, nullptr, vb16, S_LEN, NKV, DMODEL);

    qknorm_b16<<<(S_LEN * NHEAD) / 4, blk, 0, stream>>>(qf, qn_g + i * DHEAD, qb16, S_LEN * NHEAD);
    qknorm_b16<<<(S_LEN * KVHEAD) / 4, blk, 0, stream>>>(kf, kn_g + i * DHEAD, kb16, S_LEN * KVHEAD);

    attn_fwd<<<dim3(S_LEN / 64, NHEAD), blk, 0, stream>>>(qb16, kb16, vb16, ao16);

    // h2 = ao @ wo + hb  (f32 + bf16 copies)
    gemm_bt<0, false, true, true, true><<<dim3(DMODEL / 128, S_LEN / 128), blk, 0, stream>>>(
        ao16, woT, nullptr, hb, h2, h216, S_LEN, DMODEL, NQ);
    // ffi = gelu(h2 @ w1 + b1)  (bf16)
    gemm_bt<1, true, false, false, true><<<dim3(INNER_DIM / 128, S_LEN / 128), blk, 0, stream>>>(
        h216, w1T, b1_i, nullptr, nullptr, ffi16, S_LEN, INNER_DIM, DMODEL);
    // pre = ffi @ w2 + b2 + h2  (f32)
    gemm_bt<0, true, true, true, false><<<dim3(DMODEL / 128, S_LEN / 128), blk, 0, stream>>>(
        ffi16, w2T, b2_i, h2, pre, nullptr, S_LEN, DMODEL, INNER_DIM);

    ln2048<<<S_LEN, blk, 0, stream>>>(pre, model_g, model_b, x);
  }

  // head
  wtrans<<<dim3(VOCAB_PAD / 32, DMODEL / 32), blk, 0, stream>>>(head_w, headT, DMODEL, VOCAB, VOCAB_PAD);
  ln2048b<<<S_LEN, blk, 0, stream>>>(x, head_g, head_b, hn16);
  gemm_bt<0, true, false, true, false><<<dim3(VOCAB_PAD / 128, S_LEN / 128), blk, 0, stream>>>(
      hn16, headT, head_bias, nullptr, out, nullptr, S_LEN, VOCAB, DMODEL);
}

// Round 3
// 2175.502 us; speedup vs baseline: 4.0971x; 1.3704x over previous
//
#include <hip/hip_runtime.h>
#include <math.h>

#define S_LEN 2048
#define DMODEL 2048
#define NHEAD 16
#define KVHEAD 2
#define DHEAD 128
#define NLAYER 4
#define VOCAB 10000
#define INNER_DIM 8192
#define LN_EPS 1e-5f
#define VOCAB_PAD 10240  // 40*256
#define QKVN 2560        // 2048 q + 256 k + 256 v

typedef __attribute__((ext_vector_type(4))) float f32x4;
typedef __attribute__((ext_vector_type(2))) float f32x2;
typedef __attribute__((ext_vector_type(8))) short s16x8;
typedef __attribute__((ext_vector_type(4))) short s16x4;

__device__ __forceinline__ short f2bf(float f) {
  union { float f; unsigned u; } v; v.f = f;
  unsigned r = v.u + 0x7FFFu + ((v.u >> 16) & 1u);  // RNE
  return (short)(r >> 16);
}

__device__ __forceinline__ float gelu_tanh(float x) {
  float x3 = x * x * x;
  return 0.5f * x * (1.0f + tanhf(0.7978845608028654f * (x + 0.044715f * x3)));
}

__device__ __forceinline__ void glds16(const void* g, void* l) {
  __builtin_amdgcn_global_load_lds(
      (const __attribute__((address_space(1))) unsigned int*)g,
      (__attribute__((address_space(3))) unsigned int*)l, 16, 0, 0);
}

// ---------------- weight transpose 64x64 tiles: W[K][N] -> WT[NP][K] bf16 --
__global__ __launch_bounds__(256)
void wtrans64(const float* __restrict__ W, short* __restrict__ WT,
              int K, int N, int NP) {
  __shared__ float ld[64][65];
  const int n0 = blockIdx.x * 64, k0 = blockIdx.y * 64;
  const int tid = threadIdx.x;
  const int rbase = tid >> 4;
  const int c4 = (tid & 15) * 4;
#pragma unroll
  for (int q = 0; q < 4; ++q) {
    int kk = rbase + q * 16;
    const float* wp = W + (size_t)(k0 + kk) * N + n0 + c4;
    float v0, v1, v2, v3;
    if (n0 + c4 + 3 < N) {
      f32x4 v = *(const f32x4*)wp;
      v0 = v[0]; v1 = v[1]; v2 = v[2]; v3 = v[3];
    } else {
      v0 = (n0 + c4 + 0 < N) ? wp[0] : 0.f;
      v1 = (n0 + c4 + 1 < N) ? wp[1] : 0.f;
      v2 = (n0 + c4 + 2 < N) ? wp[2] : 0.f;
      v3 = (n0 + c4 + 3 < N) ? wp[3] : 0.f;
    }
    ld[kk][c4 + 0] = v0; ld[kk][c4 + 1] = v1;
    ld[kk][c4 + 2] = v2; ld[kk][c4 + 3] = v3;
  }
  __syncthreads();
#pragma unroll
  for (int s = 0; s < 2; ++s) {
    int lin = tid + s * 256;
    int nn = lin >> 3;
    int ks = lin & 7;
    int n = n0 + nn;
    if (n < NP) {
      s16x8 o;
#pragma unroll
      for (int j = 0; j < 8; ++j)
        o[j] = (n < N) ? f2bf(ld[ks * 8 + j][nn]) : (short)0;
      *(s16x8*)&WT[(size_t)n * K + k0 + ks * 8] = o;
    }
  }
}

// ---------------- embedding gather ----------------
__global__ __launch_bounds__(256)
void embed_gather(const int* __restrict__ text, const float* __restrict__ ew,
                  float* __restrict__ out) {
  const int row = blockIdx.x;
  const int tok = text[row];
  const float* src = ew + (size_t)tok * DMODEL;
  float* dst = out + (size_t)row * DMODEL;
#pragma unroll
  for (int i = 0; i < 2; ++i) {
    int idx = (threadIdx.x + i * 256) * 4;
    *(f32x4*)(dst + idx) = *(const f32x4*)(src + idx);
  }
}

// ---------------- triple LayerNorm: model -> block -> attn ----------------
// reads in row, writes hb (block-LN out, f32) and hn16 (attn-LN out, bf16)
__global__ __launch_bounds__(256)
void ln_triple(const float* __restrict__ in,
               const float* __restrict__ mg, const float* __restrict__ mb,
               const float* __restrict__ bg, const float* __restrict__ bb,
               const float* __restrict__ ag, const float* __restrict__ ab,
               float* __restrict__ hb, short* __restrict__ hn16) {
  const int row = blockIdx.x;
  const int tid = threadIdx.x;
  const int wave = tid >> 6;
  __shared__ float rs[3][4], rs2[3][4];
  float v[8];
  const float* x = in + (size_t)row * DMODEL;
#pragma unroll
  for (int i = 0; i < 8; ++i) v[i] = x[tid + i * 256];
#pragma unroll
  for (int rnd = 0; rnd < 3; ++rnd) {
    float s = 0.f, s2 = 0.f;
#pragma unroll
    for (int i = 0; i < 8; ++i) { s += v[i]; s2 += v[i] * v[i]; }
#pragma unroll
    for (int off = 1; off < 64; off <<= 1) {
      s += __shfl_xor(s, off); s2 += __shfl_xor(s2, off);
    }
    if ((tid & 63) == 0) { rs[rnd][wave] = s; rs2[rnd][wave] = s2; }
    __syncthreads();
    s = rs[rnd][0] + rs[rnd][1] + rs[rnd][2] + rs[rnd][3];
    s2 = rs2[rnd][0] + rs2[rnd][1] + rs2[rnd][2] + rs2[rnd][3];
    const float mean = s * (1.f / DMODEL);
    const float var = s2 * (1.f / DMODEL) - mean * mean;
    const float rstd = rsqrtf(var + LN_EPS);
    const float* gg = (rnd == 0) ? mg : (rnd == 1) ? bg : ag;
    const float* bbv = (rnd == 0) ? mb : (rnd == 1) ? bb : ab;
#pragma unroll
    for (int i = 0; i < 8; ++i) {
      int idx = tid + i * 256;
      v[i] = (v[i] - mean) * rstd * gg[idx] + bbv[idx];
    }
    if (rnd == 1) {
      float* o = hb + (size_t)row * DMODEL;
#pragma unroll
      for (int i = 0; i < 8; ++i) o[tid + i * 256] = v[i];
    }
  }
  short* o = hn16 + (size_t)row * DMODEL;
#pragma unroll
  for (int i = 0; i < 8; ++i) o[tid + i * 256] = f2bf(v[i]);
}

// ---------------- dual LN (model -> head), bf16 out ----------------
__global__ __launch_bounds__(256)
void ln_dual(const float* __restrict__ in,
             const float* __restrict__ mg, const float* __restrict__ mb,
             const float* __restrict__ hg, const float* __restrict__ hbv,
             short* __restrict__ out16) {
  const int row = blockIdx.x;
  const int tid = threadIdx.x;
  const int wave = tid >> 6;
  __shared__ float rs[2][4], rs2[2][4];
  float v[8];
  const float* x = in + (size_t)row * DMODEL;
#pragma unroll
  for (int i = 0; i < 8; ++i) v[i] = x[tid + i * 256];
#pragma unroll
  for (int rnd = 0; rnd < 2; ++rnd) {
    float s = 0.f, s2 = 0.f;
#pragma unroll
    for (int i = 0; i < 8; ++i) { s += v[i]; s2 += v[i] * v[i]; }
#pragma unroll
    for (int off = 1; off < 64; off <<= 1) {
      s += __shfl_xor(s, off); s2 += __shfl_xor(s2, off);
    }
    if ((tid & 63) == 0) { rs[rnd][wave] = s; rs2[rnd][wave] = s2; }
    __syncthreads();
    s = rs[rnd][0] + rs[rnd][1] + rs[rnd][2] + rs[rnd][3];
    s2 = rs2[rnd][0] + rs2[rnd][1] + rs2[rnd][2] + rs2[rnd][3];
    const float mean = s * (1.f / DMODEL);
    const float var = s2 * (1.f / DMODEL) - mean * mean;
    const float rstd = rsqrtf(var + LN_EPS);
    const float* gg = (rnd == 0) ? mg : hg;
    const float* bbv = (rnd == 0) ? mb : hbv;
#pragma unroll
    for (int i = 0; i < 8; ++i) {
      int idx = tid + i * 256;
      v[i] = (v[i] - mean) * rstd * gg[idx] + bbv[idx];
    }
  }
  short* o = out16 + (size_t)row * DMODEL;
#pragma unroll
  for (int i = 0; i < 8; ++i) o[tid + i * 256] = f2bf(v[i]);
}

// ---------------- qk-norm on strided rows of qkv buffer -> packed bf16 ----
template<int NH>
__global__ __launch_bounds__(256)
void qknorm_s(const float* __restrict__ base, int headOff,
              const float* __restrict__ g, short* __restrict__ out, int nrows) {
  const int row = blockIdx.x * 4 + (threadIdx.x >> 6);
  const int lane = threadIdx.x & 63;
  if (row >= nrows) return;
  const int s = row / NH, h = row % NH;
  const float* p = base + (size_t)s * QKVN + headOff + h * DHEAD;
  f32x2 t = *(const f32x2*)(p + lane * 2);
  float sm = t[0] + t[1];
  float s2 = t[0] * t[0] + t[1] * t[1];
#pragma unroll
  for (int off = 1; off < 64; off <<= 1) {
    sm += __shfl_xor(sm, off); s2 += __shfl_xor(s2, off);
  }
  const float mean = sm * (1.f / DHEAD);
  const float var = s2 * (1.f / DHEAD) - mean * mean;
  const float rstd = rsqrtf(var + LN_EPS);
  short* o = out + (size_t)row * DHEAD;
  o[lane * 2] = f2bf((t[0] - mean) * rstd * g[lane * 2]);
  o[lane * 2 + 1] = f2bf((t[1] - mean) * rstd * g[lane * 2 + 1]);
}

// ---------------- v slice convert f32 -> bf16 ----------------
__global__ __launch_bounds__(256)
void vconv(const float* __restrict__ qkvf, short* __restrict__ vb16) {
  int i = blockIdx.x * 256 + threadIdx.x;   // over S*256/4
  int s = i >> 6, c4 = (i & 63) * 4;
  f32x4 v = *(const f32x4*)(qkvf + (size_t)s * QKVN + 2048 + 256 + c4);
  s16x4 o;
  o[0] = f2bf(v[0]); o[1] = f2bf(v[1]); o[2] = f2bf(v[2]); o[3] = f2bf(v[3]);
  *(s16x4*)&vb16[(size_t)s * 256 + c4] = o;
}

// ---------------- double-buffered phased bf16 GEMM -----------------------
// C[M,N] = act(A[M,K] @ BT[N,K]^T + bias) (+res). 2-phase/K-tile, dbuf LDS,
// counted drain once per tile, setprio around MFMA, XCD-swizzled grid.
template<int BM, int BN, int BK, int WM, int WN, int ACT, bool BIAS, bool RES,
         bool WF, bool WB>
__global__ __launch_bounds__(WM * WN * 64)
void gemm_db(const short* __restrict__ A, const short* __restrict__ BT,
             const float* __restrict__ bias, const float* __restrict__ res,
             float* __restrict__ Cf, short* __restrict__ Cb,
             int M, int N, int K) {
  constexpr int THREADS = WM * WN * 64;
  constexpr int MR = BM / WM / 16;       // m-frags per wave
  constexpr int NR = BN / WN / 16;       // n-frags per wave
  constexpr int KH = BK / 32;            // k-halves per tile
  constexpr int SLOTS = BK / 8;          // 16B slots per LDS row
  constexpr int SMASK = SLOTS - 1;
  constexpr int RSH = (SLOTS == 8) ? 0 : 1;  // swizzle row shift
  constexpr int CSH = (SLOTS == 8) ? 3 : 2;  // chunk->row shift
  constexpr int NI = (BM * BK) / (THREADS * 8);  // glds16 instrs per side
  __shared__ short As[2][BM * BK];
  __shared__ short Bs[2][BN * BK];
  const int tid = threadIdx.x;
  const int wave = tid >> 6, lane = tid & 63;
  const int g = lane >> 4, r = lane & 15;
  const int wm = wave / WN, wn = wave % WN;

  // XCD-aware bijective swizzle (requires nwg % 8 == 0, true for all grids)
  const int GY = gridDim.y;
  int lin = blockIdx.x + blockIdx.y * gridDim.x;
  int nwg = gridDim.x * GY;
  int sw = ((nwg & 7) == 0) ? ((lin & 7) * (nwg >> 3) + (lin >> 3)) : lin;
  const int bm = (sw % GY) * BM;
  const int bn = (sw / GY) * BN;

  const short* gsrc[2 * NI];
  short* ldst[2][2 * NI];
#pragma unroll
  for (int i = 0; i < NI; ++i) {
    int c = i * THREADS + tid;
    int row = c >> CSH;
    int slot = c & SMASK;
    int col = ((slot ^ ((row >> RSH) & SMASK)) << 3);
    gsrc[i] = A + (size_t)(bm + row) * K + col;
    gsrc[NI + i] = BT + (size_t)(bn + row) * K + col;
    int base = (i * THREADS + (wave << 6)) << 3;
    ldst[0][i] = &As[0][base]; ldst[0][NI + i] = &Bs[0][base];
    ldst[1][i] = &As[1][base]; ldst[1][NI + i] = &Bs[1][base];
  }

  f32x4 acc[MR][NR] = {};
  const int NT = K / BK;

  // prologue: stage tile 0
#pragma unroll
  for (int i = 0; i < 2 * NI; ++i) glds16(gsrc[i], ldst[0][i]);
  asm volatile("s_waitcnt vmcnt(0)" ::: "memory");
  __syncthreads();

  for (int t = 0; t < NT; ++t) {
    const int cur = t & 1;
    const short* as = As[cur];
    const short* bs = Bs[cur];
    s16x8 bfr[NR][KH], af[MR / 2][KH];
    // ---- phase 0: B-frags + first m-half A-frags ----
#pragma unroll
    for (int n = 0; n < NR; ++n) {
      int rr = wn * (NR * 16) + n * 16 + r;
#pragma unroll
      for (int kk = 0; kk < KH; ++kk) {
        int lg = kk * 4 + g;
        bfr[n][kk] = *(const s16x8*)&bs[rr * BK + ((lg ^ ((rr >> RSH) & SMASK)) << 3)];
      }
    }
#pragma unroll
    for (int mm = 0; mm < MR / 2; ++mm) {
      int rr = wm * (MR * 16) + mm * 16 + r;
#pragma unroll
      for (int kk = 0; kk < KH; ++kk) {
        int lg = kk * 4 + g;
        af[mm][kk] = *(const s16x8*)&as[rr * BK + ((lg ^ ((rr >> RSH) & SMASK)) << 3)];
      }
    }
    if (t + 1 < NT) {
#pragma unroll
      for (int i = 0; i < 2 * NI; ++i) glds16(gsrc[i] + (t + 1) * BK, ldst[cur ^ 1][i]);
    }
    asm volatile("s_waitcnt lgkmcnt(0)" ::: "memory");
    __builtin_amdgcn_sched_barrier(0);
    __builtin_amdgcn_s_setprio(1);
#pragma unroll
    for (int mm = 0; mm < MR / 2; ++mm)
#pragma unroll
      for (int n = 0; n < NR; ++n)
#pragma unroll
        for (int kk = 0; kk < KH; ++kk)
          acc[mm][n] = __builtin_amdgcn_mfma_f32_16x16x32_bf16(af[mm][kk], bfr[n][kk], acc[mm][n], 0, 0, 0);
    __builtin_amdgcn_s_setprio(0);
    __builtin_amdgcn_s_barrier();
    // ---- phase 1: second m-half ----
#pragma unroll
    for (int mm = 0; mm < MR / 2; ++mm) {
      int rr = wm * (MR * 16) + (MR / 2 + mm) * 16 + r;
#pragma unroll
      for (int kk = 0; kk < KH; ++kk) {
        int lg = kk * 4 + g;
        af[mm][kk] = *(const s16x8*)&as[rr * BK + ((lg ^ ((rr >> RSH) & SMASK)) << 3)];
      }
    }
    asm volatile("s_waitcnt lgkmcnt(0)" ::: "memory");
    __builtin_amdgcn_sched_barrier(0);
    __builtin_amdgcn_s_setprio(1);
#pragma unroll
    for (int mm = 0; mm < MR / 2; ++mm)
#pragma unroll
      for (int n = 0; n < NR; ++n)
#pragma unroll
        for (int kk = 0; kk < KH; ++kk)
          acc[MR / 2 + mm][n] = __builtin_amdgcn_mfma_f32_16x16x32_bf16(af[mm][kk], bfr[n][kk], acc[MR / 2 + mm][n], 0, 0, 0);
    __builtin_amdgcn_s_setprio(0);
    __syncthreads();  // drains vmcnt (next tile staged) + aligns waves
  }

  // epilogue
#pragma unroll
  for (int m = 0; m < MR; ++m) {
    int row = bm + wm * (MR * 16) + m * 16 + g * 4;
#pragma unroll
    for (int n = 0; n < NR; ++n) {
      int col = bn + wn * (NR * 16) + n * 16 + r;
      if (col < N) {
#pragma unroll
        for (int j = 0; j < 4; ++j) {
          float v = acc[m][n][j];
          if (BIAS) v += bias[col];
          if (ACT) v = gelu_tanh(v);
          if (RES) v += res[(size_t)(row + j) * N + col];
          if (WF) Cf[(size_t)(row + j) * N + col] = v;
          if (WB) Cb[(size_t)(row + j) * N + col] = f2bf(v);
        }
      }
    }
  }
}

// ---------------- Flash attention (causal, GQA), bf16 in/out -------------
__global__ __launch_bounds__(256)
void attn_fwd(const short* __restrict__ qbuf, const short* __restrict__ kbuf,
              const short* __restrict__ vbuf, short* __restrict__ obuf) {
  __shared__ short Qs[64][136];
  __shared__ short Ks[32][136];
  __shared__ short Vt[128][40];   // [d][j ^ f(d)], f(d)=((d>>3)&3)<<3
  __shared__ short Ps[4][16][40];
  const int tid = threadIdx.x;
  // XCD swizzle: group q-tiles of the same head per XCD (KV L2 locality)
  int lin = blockIdx.x + blockIdx.y * gridDim.x;  // 32 x 16 grid
  int sw = (lin & 7) * 64 + (lin >> 3);
  const int qbase = (sw & 31) * 64;
  const int h = sw >> 5;
  const int kh = h >> 3;
  const int wave = tid >> 6;
  const int lane = tid & 63;
  const int g = lane >> 4;
  const int r = lane & 15;

#pragma unroll
  for (int i = 0; i < 4; ++i) {
    int idx = tid + i * 256;
    int row = idx >> 4;
    int c8 = (idx & 15) << 3;
    s16x8 v = *(const s16x8*)(qbuf + (size_t)(qbase + row) * DMODEL + h * DHEAD + c8);
    *(s16x8*)&Qs[row][c8] = v;
  }

  f32x4 O[8];
#pragma unroll
  for (int d = 0; d < 8; ++d) O[d] = (f32x4){0.f, 0.f, 0.f, 0.f};
  float mst[4], lst[4];
#pragma unroll
  for (int j = 0; j < 4; ++j) { mst[j] = -1e30f; lst[j] = 0.f; }
  const int nt = (qbase + 64) >> 5;
  const int qrow0 = qbase + wave * 16;

  for (int jt = 0; jt < nt; ++jt) {
    const int jb = jt * 32;
    __syncthreads();
#pragma unroll
    for (int i = 0; i < 2; ++i) {
      int idx = tid + i * 256;
      int row = idx >> 4;
      int c8 = (idx & 15) << 3;
      s16x8 kv = *(const s16x8*)(kbuf + (size_t)(jb + row) * (KVHEAD * DHEAD) + kh * DHEAD + c8);
      *(s16x8*)&Ks[row][c8] = kv;
      s16x8 vv = *(const s16x8*)(vbuf + (size_t)(jb + row) * (KVHEAD * DHEAD) + kh * DHEAD + c8);
#pragma unroll
      for (int u = 0; u < 8; ++u) {
        int d = c8 + u;
        Vt[d][row ^ (((d >> 3) & 3) << 3)] = vv[u];
      }
    }
    __syncthreads();

    f32x4 sc[2];
    sc[0] = (f32x4){0.f, 0.f, 0.f, 0.f};
    sc[1] = (f32x4){0.f, 0.f, 0.f, 0.f};
    __builtin_amdgcn_s_setprio(1);
#pragma unroll
    for (int n = 0; n < 2; ++n)
#pragma unroll
      for (int kc = 0; kc < 4; ++kc) {
        s16x8 a = *(const s16x8*)&Qs[wave * 16 + r][kc * 32 + g * 8];
        s16x8 bb = *(const s16x8*)&Ks[n * 16 + r][kc * 32 + g * 8];
        sc[n] = __builtin_amdgcn_mfma_f32_16x16x32_bf16(a, bb, sc[n], 0, 0, 0);
      }
    __builtin_amdgcn_s_setprio(0);
    const float scale = 0.08838834764831845f;
    float pmax[4];
#pragma unroll
    for (int j = 0; j < 4; ++j) {
      int irow = qrow0 + g * 4 + j;
#pragma unroll
      for (int n = 0; n < 2; ++n) {
        int jcol = jb + n * 16 + r;
        sc[n][j] = (jcol <= irow) ? sc[n][j] * scale : -1e30f;
      }
      pmax[j] = fmaxf(sc[0][j], sc[1][j]);
    }
#pragma unroll
    for (int off = 1; off < 16; off <<= 1)
#pragma unroll
      for (int j = 0; j < 4; ++j) pmax[j] = fmaxf(pmax[j], __shfl_xor(pmax[j], off));

    float alpha[4], rsum[4];
#pragma unroll
    for (int j = 0; j < 4; ++j) {
      float mnew = fmaxf(mst[j], pmax[j]);
      alpha[j] = __expf(mst[j] - mnew);
      mst[j] = mnew;
      sc[0][j] = __expf(sc[0][j] - mnew);
      sc[1][j] = __expf(sc[1][j] - mnew);
      rsum[j] = sc[0][j] + sc[1][j];
    }
#pragma unroll
    for (int off = 1; off < 16; off <<= 1)
#pragma unroll
      for (int j = 0; j < 4; ++j) rsum[j] += __shfl_xor(rsum[j], off);
#pragma unroll
    for (int j = 0; j < 4; ++j) lst[j] = lst[j] * alpha[j] + rsum[j];
#pragma unroll
    for (int d = 0; d < 8; ++d)
#pragma unroll
      for (int j = 0; j < 4; ++j) O[d][j] *= alpha[j];
#pragma unroll
    for (int j = 0; j < 4; ++j) {
      Ps[wave][g * 4 + j][r] = f2bf(sc[0][j]);
      Ps[wave][g * 4 + j][16 + r] = f2bf(sc[1][j]);
    }
    s16x8 a = *(const s16x8*)&Ps[wave][r][g * 8];
    __builtin_amdgcn_s_setprio(1);
#pragma unroll
    for (int d = 0; d < 8; ++d) {
      int dd = d * 16 + r;
      s16x8 bb = *(const s16x8*)&Vt[dd][(g << 3) ^ (((dd >> 3) & 3) << 3)];
      O[d] = __builtin_amdgcn_mfma_f32_16x16x32_bf16(a, bb, O[d], 0, 0, 0);
    }
    __builtin_amdgcn_s_setprio(0);
  }
  float linv[4];
#pragma unroll
  for (int j = 0; j < 4; ++j) linv[j] = 1.f / lst[j];
#pragma unroll
  for (int d = 0; d < 8; ++d)
#pragma unroll
    for (int j = 0; j < 4; ++j)
      obuf[(size_t)(qrow0 + g * 4 + j) * DMODEL + h * DHEAD + d * 16 + r] =
          f2bf(O[d][j] * linv[j]);
}

// ---------------- host side ----------------
extern "C" void kernel_launch(void* const* d_in, const int* in_sizes, int n_in,
                              void* d_out, int out_size, void* d_ws, size_t ws_size,
                              hipStream_t stream) {
  const int* text = (const int*)d_in[0];
  const float* embed_w = (const float*)d_in[1];
  const float* model_g = (const float*)d_in[2];
  const float* model_b = (const float*)d_in[3];
  const float* blk_g = (const float*)d_in[4];
  const float* blk_b = (const float*)d_in[5];
  const float* attn_g = (const float*)d_in[6];
  const float* attn_b = (const float*)d_in[7];
  const float* wq = (const float*)d_in[8];
  const float* wk = (const float*)d_in[9];
  const float* wv = (const float*)d_in[10];
  const float* wo = (const float*)d_in[11];
  const float* qn_g = (const float*)d_in[12];
  const float* kn_g = (const float*)d_in[13];
  const float* w1 = (const float*)d_in[14];
  const float* b1 = (const float*)d_in[15];
  const float* w2 = (const float*)d_in[16];
  const float* b2 = (const float*)d_in[17];
  const float* head_g = (const float*)d_in[18];
  const float* head_b = (const float*)d_in[19];
  const float* head_w = (const float*)d_in[20];
  const float* head_bias = (const float*)d_in[21];
  float* out = (float*)d_out;

  const size_t SD = (size_t)S_LEN * DMODEL;
  const size_t SKV = (size_t)S_LEN * KVHEAD * DHEAD;
  const size_t SI = (size_t)S_LEN * INNER_DIM;
  const size_t WD = (size_t)DMODEL * DMODEL;
  const size_t WKV = (size_t)DMODEL * KVHEAD * DHEAD;
  const size_t WI = (size_t)DMODEL * INNER_DIM;

  char* p = (char*)d_ws;
  float* xres  = (float*)p; p += SD * 4;            // embed out / FFN residual out
  float* hb    = (float*)p; p += SD * 4;
  float* h2    = (float*)p; p += SD * 4;
  float* qkvf  = (float*)p; p += (size_t)S_LEN * QKVN * 4;
  short* hn16  = (short*)p; p += SD * 2;
  short* h216  = (short*)p; p += SD * 2;
  short* ao16  = (short*)p; p += SD * 2;
  short* ffi16 = (short*)p; p += SI * 2;
  short* qb16  = (short*)p; p += SD * 2;
  short* kb16  = (short*)p; p += SKV * 2;
  short* vb16  = (short*)p; p += SKV * 2;
  short* wqkvT = (short*)p; p += (size_t)QKVN * DMODEL * 2;
  short* woT   = (short*)p; p += WD * 2;
  short* w1T   = (short*)p; p += WI * 2;
  short* w2T   = (short*)p; p += WI * 2;
  short* headT = w1T;  // reused after last layer (needs 10240*2048*2 = 42MB < 134MB)

  dim3 blk(256);
  embed_gather<<<S_LEN, blk, 0, stream>>>(text, embed_w, xres);

  for (int i = 0; i < NLAYER; ++i) {
    const float* wq_i = wq + (size_t)i * WD;
    const float* wk_i = wk + (size_t)i * WKV;
    const float* wv_i = wv + (size_t)i * WKV;
    const float* wo_i = wo + (size_t)i * WD;
    const float* w1_i = w1 + (size_t)i * WI;
    const float* b1_i = b1 + (size_t)i * INNER_DIM;
    const float* w2_i = w2 + (size_t)i * WI;
    const float* b2_i = b2 + (size_t)i * DMODEL;

    wtrans64<<<dim3(32, 32), blk, 0, stream>>>(wq_i, wqkvT, DMODEL, DMODEL, DMODEL);
    wtrans64<<<dim3(4, 32), blk, 0, stream>>>(wk_i, wqkvT + (size_t)2048 * DMODEL, DMODEL, 256, 256);
    wtrans64<<<dim3(4, 32), blk, 0, stream>>>(wv_i, wqkvT + (size_t)2304 * DMODEL, DMODEL, 256, 256);
    wtrans64<<<dim3(32, 32), blk, 0, stream>>>(wo_i, woT, DMODEL, DMODEL, DMODEL);
    wtrans64<<<dim3(128, 32), blk, 0, stream>>>(w1_i, w1T, DMODEL, INNER_DIM, INNER_DIM);
    wtrans64<<<dim3(32, 128), blk, 0, stream>>>(w2_i, w2T, INNER_DIM, DMODEL, DMODEL);

    ln_triple<<<S_LEN, blk, 0, stream>>>(xres, model_g, model_b,
                                         blk_g + i * DMODEL, blk_b + i * DMODEL,
                                         attn_g + i * DMODEL, attn_b + i * DMODEL,
                                         hb, hn16);

    // qkv fused GEMM: [S,2048] @ [2048,2560] -> qkvf
    gemm_db<128, 128, 64, 2, 2, 0, false, false, true, false>
        <<<dim3(QKVN / 128, S_LEN / 128), dim3(256), 0, stream>>>(
        hn16, wqkvT, nullptr, nullptr, qkvf, nullptr, S_LEN, QKVN, DMODEL);

    qknorm_s<NHEAD><<<(S_LEN * NHEAD) / 4, blk, 0, stream>>>(
        qkvf, 0, qn_g + i * DHEAD, qb16, S_LEN * NHEAD);
    qknorm_s<KVHEAD><<<(S_LEN * KVHEAD) / 4, blk, 0, stream>>>(
        qkvf, 2048, kn_g + i * DHEAD, kb16, S_LEN * KVHEAD);
    vconv<<<(S_LEN * 64) / 256, blk, 0, stream>>>(qkvf, vb16);

    attn_fwd<<<dim3(S_LEN / 64, NHEAD), blk, 0, stream>>>(qb16, kb16, vb16, ao16);

    // h2 = ao @ wo + hb
    gemm_db<128, 128, 64, 2, 2, 0, false, true, true, true>
        <<<dim3(DMODEL / 128, S_LEN / 128), dim3(256), 0, stream>>>(
        ao16, woT, nullptr, hb, h2, h216, S_LEN, DMODEL, DMODEL);
    // ffi = gelu(h2 @ w1 + b1)   (256x256 tiles)
    gemm_db<256, 256, 32, 2, 4, 1, true, false, false, true>
        <<<dim3(INNER_DIM / 256, S_LEN / 256), dim3(512), 0, stream>>>(
        h216, w1T, b1_i, nullptr, nullptr, ffi16, S_LEN, INNER_DIM, DMODEL);
    // pre = ffi @ w2 + b2 + h2 -> xres
    gemm_db<128, 128, 64, 2, 2, 0, true, true, true, false>
        <<<dim3(DMODEL / 128, S_LEN / 128), dim3(256), 0, stream>>>(
        ffi16, w2T, b2_i, h2, xres, nullptr, S_LEN, DMODEL, INNER_DIM);
  }

  // head
  wtrans64<<<dim3(VOCAB_PAD / 64, 32), blk, 0, stream>>>(head_w, headT, DMODEL, VOCAB, VOCAB_PAD);
  ln_dual<<<S_LEN, blk, 0, stream>>>(xres, model_g, model_b, head_g, head_b, hn16);
  gemm_db<256, 256, 32, 2, 4, 0, true, false, true, false>
      <<<dim3(VOCAB_PAD / 256, S_LEN / 256), dim3(512), 0, stream>>>(
      hn16, headT, head_bias, nullptr, out, nullptr, S_LEN, VOCAB, DMODEL);
}